// Round 1
// baseline (368.753 us; speedup 1.0000x reference)
//
#include <hip/hip_runtime.h>
#include <hip/hip_bf16.h>

// Problem constants (from reference setup_inputs)
constexpr int B = 128;
constexpr int A = 8732;
constexpr int C = 21;
constexpr int M = 8;

// ---------------------------------------------------------------------------
// K0: zero accumulators
// accf[0]=conf_pos, accf[1]=loc_sum, accf[2]=conf_hard_neg ; npt = n_pos_total
__global__ void k_init(float* accf, int* npt) {
    int t = threadIdx.x;
    if (t < 3) accf[t] = 0.f;
    if (t == 3) *npt = 0;
}

// ---------------------------------------------------------------------------
// K1: per-batch matching. One block per batch row.
__global__ __launch_bounds__(256) void k_match(
    const float* __restrict__ boxes,    // [B,M,4] raw pixel xy
    const int*   __restrict__ labels,   // [B,M]
    const float* __restrict__ anchors,  // [A,4] cxcy
    int*         __restrict__ packed,   // [B,A]  lab | (obj<<8)
    int*         __restrict__ n_pos,    // [B]
    int*         __restrict__ npt)
{
    __shared__ float         s_iou[A];
    __shared__ unsigned char s_obj[A];
    __shared__ float s_bval[M][256];
    __shared__ int   s_bidx[M][256];
    __shared__ int   s_force[M];
    __shared__ int   s_cnt[256];
    __shared__ float s_box[M][4];
    __shared__ int   s_lab[M];

    const int b = blockIdx.x;
    const int t = threadIdx.x;

    if (t < M * 4) ((float*)s_box)[t] = boxes[b * M * 4 + t];
    if (t < M)     s_lab[t] = labels[b * M + t];
    __syncthreads();

    // scaled boxes (match reference: boxes / 300.0) + areas
    float bb[M][4], barea[M];
#pragma unroll
    for (int m = 0; m < M; m++) {
        bb[m][0] = s_box[m][0] / 300.f;
        bb[m][1] = s_box[m][1] / 300.f;
        bb[m][2] = s_box[m][2] / 300.f;
        bb[m][3] = s_box[m][3] / 300.f;
        barea[m] = (bb[m][2] - bb[m][0]) * (bb[m][3] - bb[m][1]);
    }

    float bestv[M];
    int   besti[M];
#pragma unroll
    for (int m = 0; m < M; m++) { bestv[m] = -1.f; besti[m] = 0; }

    for (int a = t; a < A; a += 256) {
        float cx = anchors[a * 4 + 0], cy = anchors[a * 4 + 1];
        float w  = anchors[a * 4 + 2], h  = anchors[a * 4 + 3];
        float ax1 = cx - w / 2.0f, ay1 = cy - h / 2.0f;
        float ax2 = cx + w / 2.0f, ay2 = cy + h / 2.0f;
        float aarea = (ax2 - ax1) * (ay2 - ay1);  // matches ref area_b from xy form

        float bmax = -1.f; int bm = 0;
#pragma unroll
        for (int m = 0; m < M; m++) {
            float lx = fmaxf(bb[m][0], ax1), ly = fmaxf(bb[m][1], ay1);
            float rx = fminf(bb[m][2], ax2), ry = fminf(bb[m][3], ay2);
            float iw = fmaxf(rx - lx, 0.f), ih = fmaxf(ry - ly, 0.f);
            float inter = iw * ih;
            float iou = inter / (barea[m] + aarea - inter);
            if (iou > bmax) { bmax = iou; bm = m; }          // first-max over m
            if (iou > bestv[m]) { bestv[m] = iou; besti[m] = a; }  // first-max over a (ascending)
        }
        s_iou[a] = bmax;
        s_obj[a] = (unsigned char)bm;
    }

#pragma unroll
    for (int m = 0; m < M; m++) { s_bval[m][t] = bestv[m]; s_bidx[m][t] = besti[m]; }
    __syncthreads();

    // per-object argmax across threads; tie-break: smaller anchor index
    if (t < M) {
        float bv = -1.f; int bi = 0x7fffffff;
        for (int j = 0; j < 256; j++) {
            float v = s_bval[t][j]; int i = s_bidx[t][j];
            if (v > bv || (v == bv && i < bi)) { bv = v; bi = i; }
        }
        s_force[t] = bi;
    }
    __syncthreads();

    // numpy fancy-assign semantics: last object wins on duplicate anchors
    if (t == 0) {
        for (int m = 0; m < M; m++) {
            int a = s_force[m];
            s_obj[a] = (unsigned char)m;
            s_iou[a] = 1.0f;
        }
    }
    __syncthreads();

    int cnt = 0;
    for (int a = t; a < A; a += 256) {
        int obj = s_obj[a];
        int lab = s_lab[obj];
        if (s_iou[a] < 0.5f) lab = 0;
        packed[(size_t)b * A + a] = lab | (obj << 8);
        if (lab != 0) cnt++;
    }
    s_cnt[t] = cnt;
    __syncthreads();
    for (int s = 128; s > 0; s >>= 1) {
        if (t < s) s_cnt[t] += s_cnt[t + s];
        __syncthreads();
    }
    if (t == 0) { n_pos[b] = s_cnt[0]; atomicAdd(npt, s_cnt[0]); }
}

// ---------------------------------------------------------------------------
// K2: per-anchor cross-entropy + positive-anchor loc L1.
// Writes ce_neg in place over the packed buffer (same slot, read-then-write).
__global__ __launch_bounds__(256) void k_ce(
    const float* __restrict__ plocs,    // [B,A,4]
    const float* __restrict__ pscores,  // [B,A,C]
    const float* __restrict__ boxes,    // [B,M,4] raw pixel xy
    const float* __restrict__ anchors,  // [A,4]
    int*         __restrict__ buf,      // in: packed, out: ce_neg bits
    float*       __restrict__ accf)
{
    int idx = blockIdx.x * 256 + threadIdx.x;
    float l_pos = 0.f, l_loc = 0.f;

    if (idx < B * A) {
        int pk  = buf[idx];
        int lab = pk & 255;
        int obj = pk >> 8;

        const float* s = pscores + (size_t)idx * C;
        float mx = s[0];
#pragma unroll
        for (int c = 1; c < C; c++) mx = fmaxf(mx, s[c]);
        float sum = 0.f;
#pragma unroll
        for (int c = 0; c < C; c++) sum += __expf(s[c] - mx);
        float lse = mx + __logf(sum);
        float ce  = lse - s[lab];

        float cn = ce;
        if (lab != 0) {
            cn = 0.f;
            l_pos = ce;
            int b = idx / A;
            int a = idx - b * A;
            const float* bx = boxes + ((size_t)b * M + obj) * 4;
            const float* an = anchors + (size_t)a * 4;
            // reference quirk: raw pixel xy boxes fed into cxcy_to_gcxgcy
            float dx = (bx[0] - an[0]) / (an[2] / 10.f);
            float dy = (bx[1] - an[1]) / (an[3] / 10.f);
            float dw = logf(bx[2] / an[2]) * 5.f;
            float dh = logf(bx[3] / an[3]) * 5.f;
            const float* p = plocs + (size_t)idx * 4;
            l_loc = fabsf(p[0] - dx) + fabsf(p[1] - dy) +
                    fabsf(p[2] - dw) + fabsf(p[3] - dh);
        }
        ((float*)buf)[idx] = cn;
    }

    __shared__ float r0[256], r1[256];
    r0[threadIdx.x] = l_pos;
    r1[threadIdx.x] = l_loc;
    __syncthreads();
    for (int s = 128; s > 0; s >>= 1) {
        if (threadIdx.x < s) {
            r0[threadIdx.x] += r0[threadIdx.x + s];
            r1[threadIdx.x] += r1[threadIdx.x + s];
        }
        __syncthreads();
    }
    if (threadIdx.x == 0) {
        if (r0[0] != 0.f) atomicAdd(&accf[0], r0[0]);
        if (r1[0] != 0.f) atomicAdd(&accf[1], r1[0]);
    }
}

// ---------------------------------------------------------------------------
// K3: per-row sum of top-(3*n_pos[b]) of ce_neg via radix select.
// Exact even with ties: sum = sum(v>t) + (K - cnt_gt) * t.
__global__ __launch_bounds__(256) void k_topk(
    const float* __restrict__ ce_neg,   // [B,A] (aliased buf)
    const int*   __restrict__ n_pos,    // [B]
    float*       __restrict__ accf)     // accf[2] += row topK sum
{
    __shared__ unsigned int vals[A];
    __shared__ unsigned int hist[256];
    __shared__ unsigned int s_prefix, s_krem;
    __shared__ float        rs[256];
    __shared__ unsigned int rc[256];

    const int b = blockIdx.x;
    const int t = threadIdx.x;
    const int K = 3 * n_pos[b];
    const float* row = ce_neg + (size_t)b * A;

    for (int i = t; i < A; i += 256) vals[i] = __float_as_uint(row[i]);
    if (t == 0) { s_prefix = 0u; s_krem = (unsigned)K; }
    __syncthreads();

    if (K <= 0) return;  // uniform branch

    if (K >= A) {        // uniform branch: sum the whole row
        float s = 0.f;
        for (int i = t; i < A; i += 256) s += __uint_as_float(vals[i]);
        rs[t] = s; __syncthreads();
        for (int st = 128; st > 0; st >>= 1) {
            if (t < st) rs[t] += rs[t + st];
            __syncthreads();
        }
        if (t == 0) atomicAdd(&accf[2], rs[0]);
        return;
    }

    for (int pass = 0; pass < 4; pass++) {
        int shift = 24 - 8 * pass;
        hist[t] = 0u;
        __syncthreads();
        unsigned int pref = s_prefix;
        for (int i = t; i < A; i += 256) {
            unsigned int v = vals[i];
            if (pass == 0 || (v >> (shift + 8)) == pref)
                atomicAdd(&hist[(v >> shift) & 255u], 1u);
        }
        __syncthreads();
        if (t == 0) {
            unsigned int cum = 0, krem = s_krem, sel = 0;
            for (int i = 255; i >= 0; i--) {
                unsigned int c = hist[i];
                if (cum + c >= krem) { sel = (unsigned)i; s_krem = krem - cum; break; }
                cum += c;
            }
            s_prefix = (pref << 8) | sel;
        }
        __syncthreads();
    }

    const unsigned int tb = s_prefix;  // bits of the K-th largest value
    float sg = 0.f; unsigned int cg = 0;
    for (int i = t; i < A; i += 256) {
        unsigned int v = vals[i];
        if (v > tb) { sg += __uint_as_float(v); cg++; }
    }
    rs[t] = sg; rc[t] = cg;
    __syncthreads();
    for (int st = 128; st > 0; st >>= 1) {
        if (t < st) { rs[t] += rs[t + st]; rc[t] += rc[t + st]; }
        __syncthreads();
    }
    if (t == 0) {
        float tv = __uint_as_float(tb);
        float total = rs[0] + (float)(K - (int)rc[0]) * tv;
        atomicAdd(&accf[2], total);
    }
}

// ---------------------------------------------------------------------------
// K4: final scalar
__global__ void k_final(const float* __restrict__ accf,
                        const int* __restrict__ npt,
                        float* __restrict__ out)
{
    float n = (float)(*npt);
    float conf_loss = (accf[2] + accf[0]) / n;
    float loc_loss  = accf[1] / (n * 4.f);
    out[0] = conf_loss + loc_loss;
}

// ---------------------------------------------------------------------------
extern "C" void kernel_launch(void* const* d_in, const int* in_sizes, int n_in,
                              void* d_out, int out_size, void* d_ws, size_t ws_size,
                              hipStream_t stream)
{
    const float* plocs   = (const float*)d_in[0];  // [B,A,4]
    const float* pscores = (const float*)d_in[1];  // [B,A,C]
    const float* boxes   = (const float*)d_in[2];  // [B,M,4]
    const int*   labels  = (const int*)d_in[3];    // [B,M]
    const float* anchors = (const float*)d_in[4];  // [A,4]
    float*       out     = (float*)d_out;

    // workspace layout (elements of 4 bytes):
    // [0..2] accf, [3] n_pos_total, [8..8+B) n_pos, [8+B ..) packed/ce_neg [B*A]
    float* accf  = (float*)d_ws;
    int*   npt   = (int*)d_ws + 3;
    int*   n_pos = (int*)d_ws + 8;
    int*   buf   = (int*)d_ws + 8 + B;

    k_init<<<1, 64, 0, stream>>>(accf, npt);
    k_match<<<B, 256, 0, stream>>>(boxes, labels, anchors, buf, n_pos, npt);
    int nblk = (B * A + 255) / 256;
    k_ce<<<nblk, 256, 0, stream>>>(plocs, pscores, boxes, anchors, buf, accf);
    k_topk<<<B, 256, 0, stream>>>((const float*)buf, n_pos, accf);
    k_final<<<1, 1, 0, stream>>>(accf, npt, out);
}